// Round 8
// baseline (366.025 us; speedup 1.0000x reference)
//
#include <hip/hip_runtime.h>
#include <math.h>

constexpr float EPS = 1e-5f;
constexpr float SCALE = 0.08838834764831845f; // 1/sqrt(128)

using f32x4  = __attribute__((ext_vector_type(4))) float;
using bf16x8 = __attribute__((ext_vector_type(8))) short;
using us8    = __attribute__((ext_vector_type(8))) unsigned short;

__device__ __forceinline__ unsigned short f2b_rne(float f) {
    unsigned int x = __float_as_uint(f);
    return (unsigned short)((x + 0x7fffu + ((x >> 16) & 1u)) >> 16);
}

// XOR-swizzled element offset into a [rows][32]-us tile; k8 = 8-elem col chunk.
__device__ __forceinline__ int swz32(int row, int k8) {
    int f = (row & 3) ^ ((row >> 2) & 3);
    return row * 32 + ((k8 ^ f) << 3);
}

// ====== one-time weight prep: bf16 hi/lo split (Wp|Wk|Wv) + float4 T-pack ====
__global__ __launch_bounds__(256) void prep_weights_kernel(
    const float* __restrict__ Wp, const float* __restrict__ Wk,
    const float* __restrict__ Wv, const float* __restrict__ Wih,
    const float* __restrict__ Whh, const float* __restrict__ W1,
    const float* __restrict__ W2, const float* __restrict__ Wq,
    unsigned short* __restrict__ hi, unsigned short* __restrict__ lo,
    float4* __restrict__ wt4)
{
    int idx = blockIdx.x * 256 + threadIdx.x; // 102400 total
    if (idx < 57344) {
        float v;
        if (idx < 24576)      v = Wp[idx];
        else if (idx < 40960) v = Wk[idx - 24576];
        else                  v = Wv[idx - 40960];
        unsigned int bits = __float_as_uint(v);
        hi[idx] = (unsigned short)(bits >> 16);
        lo[idx] = f2b_rne(v - __uint_as_float(bits & 0xffff0000u));
    } else {
        int li = idx - 57344;
        const float* src; int OUT, base, K;
        if (li < 12288)      { src = Wih; OUT = 384; base = 0;     K = 128; }
        else if (li < 24576) { src = Whh; OUT = 384; base = 12288; K = 128; }
        else if (li < 32768) { src = W1;  OUT = 256; base = 24576; K = 128; }
        else if (li < 40960) { src = W2;  OUT = 128; base = 32768; K = 256; }
        else                 { src = Wq;  OUT = 128; base = 40960; K = 128; }
        int lo2 = li - base;
        int kq = lo2 / OUT, t = lo2 - kq * OUT;
        float4 v;
        v.x = src[(size_t)t * K + 4 * kq];
        v.y = src[(size_t)t * K + 4 * kq + 1];
        v.z = src[(size_t)t * K + 4 * kq + 2];
        v.w = src[(size_t)t * K + 4 * kq + 3];
        wt4[li] = v;
    }
}

// ========== mega-fused: X = LN(patch @ Wp^T + bp); k,v = X @ {Wk,Wv}^T =======
// R6/R7 verified version (unchanged).
__global__ __launch_bounds__(256, 3) void fused_proj_kv_kernel(
    const float* __restrict__ patch,
    const unsigned short* __restrict__ Wphi, const unsigned short* __restrict__ Wplo,
    const unsigned short* __restrict__ Wkhi, const unsigned short* __restrict__ Wklo,
    const unsigned short* __restrict__ Wvhi, const unsigned short* __restrict__ Wvlo,
    const float* __restrict__ biasp, const float* __restrict__ g_in,
    const float* __restrict__ b_in, const float* __restrict__ biask,
    const float* __restrict__ biasv,
    float* __restrict__ kout, float* __restrict__ vout)
{
    __shared__ __align__(16) unsigned short mem[24576];

    const int tid  = threadIdx.x;
    const int lane = tid & 63, wave = tid >> 6;
    const int ln15 = lane & 15, quad = lane >> 4;
    const int bid  = blockIdx.x;
    const int m0   = ((bid & 7) * 256 + (bid >> 3)) * 64;

    const int wrow = wave * 16;
    f32x4 acc1[8];
#pragma unroll
    for (int nt = 0; nt < 8; nt++)
#pragma unroll
        for (int r = 0; r < 4; r++) acc1[nt][r] = 0.f;

    const int arow = tid >> 2, ak8 = tid & 3;
    const float* aptr = patch + (size_t)(m0 + arow) * 192 + ak8 * 8;
    float4 pa[6][2];
#pragma unroll
    for (int t6 = 0; t6 < 6; t6++) {
        pa[t6][0] = *(const float4*)(aptr + t6 * 32);
        pa[t6][1] = *(const float4*)(aptr + t6 * 32 + 4);
    }
    us8 pbh[2], pbl[2];
    int boff[2];
#pragma unroll
    for (int i = 0; i < 2; i++) {
        int c = tid + 256 * i;
        boff[i] = (c >> 2) * 192 + (c & 3) * 8;
        pbh[i] = *(const us8*)(Wphi + boff[i]);
        pbl[i] = *(const us8*)(Wplo + boff[i]);
    }

    const int ea = swz32(wrow + ln15, quad);

#pragma unroll
    for (int st = 0; st < 6; st++) {
        {
            float va[8] = {pa[st][0].x, pa[st][0].y, pa[st][0].z, pa[st][0].w,
                           pa[st][1].x, pa[st][1].y, pa[st][1].z, pa[st][1].w};
            us8 h, l;
#pragma unroll
            for (int j = 0; j < 8; j++) {
                unsigned int bits = __float_as_uint(va[j]);
                h[j] = (unsigned short)(bits >> 16);
                l[j] = f2b_rne(va[j] - __uint_as_float(bits & 0xffff0000u));
            }
            int e = swz32(arow, ak8);
            *(us8*)&mem[e]        = h;
            *(us8*)&mem[2048 + e] = l;
        }
#pragma unroll
        for (int i = 0; i < 2; i++) {
            int c = tid + 256 * i;
            int e = swz32(c >> 2, c & 3);
            *(us8*)&mem[4096 + e] = pbh[i];
            *(us8*)&mem[8192 + e] = pbl[i];
        }
        __syncthreads();

        if (st < 5) {
            int kn = (st + 1) * 32;
#pragma unroll
            for (int i = 0; i < 2; i++) {
                pbh[i] = *(const us8*)(Wphi + boff[i] + kn);
                pbl[i] = *(const us8*)(Wplo + boff[i] + kn);
            }
        }

        bf16x8 ah = *(const bf16x8*)&mem[ea];
        bf16x8 al = *(const bf16x8*)&mem[2048 + ea];
#pragma unroll
        for (int nt = 0; nt < 8; nt++) {
            int eb = swz32(nt * 16 + ln15, quad);
            bf16x8 bh = *(const bf16x8*)&mem[4096 + eb];
            bf16x8 bl = *(const bf16x8*)&mem[8192 + eb];
            acc1[nt] = __builtin_amdgcn_mfma_f32_16x16x32_bf16(ah, bh, acc1[nt], 0, 0, 0);
            acc1[nt] = __builtin_amdgcn_mfma_f32_16x16x32_bf16(ah, bl, acc1[nt], 0, 0, 0);
            acc1[nt] = __builtin_amdgcn_mfma_f32_16x16x32_bf16(al, bh, acc1[nt], 0, 0, 0);
        }
        __syncthreads();
    }

    us8 pw[4];
#pragma unroll
    for (int i = 0; i < 4; i++) {
        const unsigned short* pl = (i >> 1) ? Wklo : Wkhi;
        int c = tid + (i & 1) * 256;
        pw[i] = *(const us8*)(pl + (size_t)(c >> 2) * 128 + (c & 3) * 8);
    }

    {
        float bb[8], gg[8], be[8];
#pragma unroll
        for (int nt = 0; nt < 8; nt++) {
            int col = nt * 16 + ln15;
            bb[nt] = biasp[col]; gg[nt] = g_in[col]; be[nt] = b_in[col];
        }
#pragma unroll
        for (int nt = 0; nt < 8; nt++)
#pragma unroll
            for (int r = 0; r < 4; r++) acc1[nt][r] += bb[nt];

        float mu[4], rs[4];
#pragma unroll
        for (int r = 0; r < 4; r++) {
            float s = 0.f, s2 = 0.f;
#pragma unroll
            for (int nt = 0; nt < 8; nt++) {
                float v = acc1[nt][r];
                s += v; s2 += v * v;
            }
#pragma unroll
            for (int off = 1; off < 16; off <<= 1) {
                s  += __shfl_xor(s,  off, 64);
                s2 += __shfl_xor(s2, off, 64);
            }
            float m = s * (1.f / 128.f);
            mu[r] = m;
            rs[r] = rsqrtf(s2 * (1.f / 128.f) - m * m + EPS);
        }
#pragma unroll
        for (int nt = 0; nt < 8; nt++)
#pragma unroll
            for (int r = 0; r < 4; r++) {
                float v = (acc1[nt][r] - mu[r]) * rs[r] * gg[nt] + be[nt];
                int row = wrow + quad * 4 + r, col = nt * 16 + ln15;
                int xi = (row * 128 + col) ^ ((row & 7) << 3);
                unsigned int bits = __float_as_uint(v);
                mem[xi]        = (unsigned short)(bits >> 16);
                mem[8192 + xi] = f2b_rne(v - __uint_as_float(bits & 0xffff0000u));
            }
    }

    const int R  = (wave & 1) * 32;
    const int Cb = (wave >> 1) * 64;
    const int xorx = (ln15 & 7) << 3;

    float bbk[4], bbv[4];
#pragma unroll
    for (int nt = 0; nt < 4; nt++) {
        int col = Cb + nt * 16 + ln15;
        bbk[nt] = biask[col];
        bbv[nt] = biasv[col];
    }

    f32x4 acc[2][4];
#pragma unroll
    for (int mt = 0; mt < 2; mt++)
#pragma unroll
        for (int nt = 0; nt < 4; nt++)
#pragma unroll
            for (int r = 0; r < 4; r++) acc[mt][nt][r] = 0.f;

#pragma unroll
    for (int s = 0; s < 8; s++) {
#pragma unroll
        for (int i = 0; i < 4; i++) {
            int c = tid + (i & 1) * 256;
            int e = 16384 + (i >> 1) * 4096 + swz32(c >> 2, c & 3);
            *(us8*)&mem[e] = pw[i];
        }
        __syncthreads();

        if (s < 7) {
            int sn = s + 1, kkn = (sn & 3) * 32;
            const unsigned short* ph = (sn >> 2) ? Wvhi : Wkhi;
            const unsigned short* po = (sn >> 2) ? Wvlo : Wklo;
#pragma unroll
            for (int i = 0; i < 4; i++) {
                const unsigned short* pl = (i >> 1) ? po : ph;
                int c = tid + (i & 1) * 256;
                pw[i] = *(const us8*)(pl + (size_t)(c >> 2) * 128 + (c & 3) * 8 + kkn);
            }
        }

        int kk = (s & 3) * 32;
        bf16x8 xh[2], xl[2];
#pragma unroll
        for (int mt = 0; mt < 2; mt++) {
            int row = R + mt * 16 + ln15;
            int ei = (row * 128 + kk + quad * 8) ^ xorx;
            xh[mt] = *(const bf16x8*)&mem[ei];
            xl[mt] = *(const bf16x8*)&mem[8192 + ei];
        }
#pragma unroll
        for (int nt = 0; nt < 4; nt++) {
            int eb = 16384 + swz32(Cb + nt * 16 + ln15, quad);
            bf16x8 wh = *(const bf16x8*)&mem[eb];
            bf16x8 wl = *(const bf16x8*)&mem[4096 + eb];
#pragma unroll
            for (int mt = 0; mt < 2; mt++) {
                acc[mt][nt] = __builtin_amdgcn_mfma_f32_16x16x32_bf16(xh[mt], wh, acc[mt][nt], 0, 0, 0);
                acc[mt][nt] = __builtin_amdgcn_mfma_f32_16x16x32_bf16(xh[mt], wl, acc[mt][nt], 0, 0, 0);
                acc[mt][nt] = __builtin_amdgcn_mfma_f32_16x16x32_bf16(xl[mt], wh, acc[mt][nt], 0, 0, 0);
            }
        }

        if (s == 3) {
#pragma unroll
            for (int mt = 0; mt < 2; mt++)
#pragma unroll
                for (int nt = 0; nt < 4; nt++)
#pragma unroll
                    for (int r = 0; r < 4; r++) {
                        size_t o = (size_t)(m0 + R + mt * 16 + quad * 4 + r) * 128
                                 + Cb + nt * 16 + ln15;
                        kout[o] = acc[mt][nt][r] + bbk[nt];
                        acc[mt][nt][r] = 0.f;
                    }
        }
        if (s < 7) __syncthreads();
    }

#pragma unroll
    for (int mt = 0; mt < 2; mt++)
#pragma unroll
        for (int nt = 0; nt < 4; nt++)
#pragma unroll
            for (int r = 0; r < 4; r++) {
                size_t o = (size_t)(m0 + R + mt * 16 + quad * 4 + r) * 128
                         + Cb + nt * 16 + ln15;
                vout[o] = acc[mt][nt][r] + bbv[nt];
            }
}

// =================== init slots + LN + q (one block per slot row) ============
__global__ __launch_bounds__(128) void init_lnq_kernel(
    const float* __restrict__ noise, const float* __restrict__ smu,
    const float* __restrict__ sls, const float* __restrict__ g_s,
    const float* __restrict__ b_s, const float4* __restrict__ WqT4,
    const float* __restrict__ bq, float* __restrict__ slots,
    float* __restrict__ q)
{
    __shared__ float s_l[128];
    __shared__ float red[4];
    const int row = blockIdx.x, tid = threadIdx.x;
    const int k = row % 3;
    float x = smu[k * 128 + tid] + expf(sls[k * 128 + tid]) * noise[row * 128 + tid];
    slots[row * 128 + tid] = x;

    float s = x, s2 = x * x;
#pragma unroll
    for (int off = 32; off >= 1; off >>= 1) {
        s += __shfl_down(s, off, 64); s2 += __shfl_down(s2, off, 64);
    }
    if ((tid & 63) == 0) { red[tid >> 6] = s; red[2 + (tid >> 6)] = s2; }
    __syncthreads();
    float S = red[0] + red[1], S2 = red[2] + red[3];
    float m = S * (1.f / 128.f);
    float r = rsqrtf(S2 * (1.f / 128.f) - m * m + EPS);
    s_l[tid] = (x - m) * r * g_s[tid] + b_s[tid];
    __syncthreads();

    float a = bq[tid];
#pragma unroll 8
    for (int kq = 0; kq < 32; kq++) {
        float4 w = WqT4[kq * 128 + tid];
        a += s_l[4 * kq] * w.x + s_l[4 * kq + 1] * w.y
           + s_l[4 * kq + 2] * w.z + s_l[4 * kq + 3] * w.w;
    }
    q[row * 128 + tid] = a;
}

// ============ fused attention: logits -> softmax(K=3) -> partial updates =====
// R7 verified version (unchanged): 256-token chunks, grid (4,B), phase-
// separated with register-double-buffered k/v streams.
__global__ __launch_bounds__(256) void attn_kernel(
    const float* __restrict__ q, const float* __restrict__ kbuf,
    const float* __restrict__ vbuf, float* __restrict__ upd_part,
    float* __restrict__ attn_out, int write_attn)
{
    __shared__ float q_l[3][132];
    __shared__ float lg[3][256];
    __shared__ float w_l[3][256];
    __shared__ float part[8][3][128];
    const int b = blockIdx.y, chunk = blockIdx.x, n0 = chunk * 256, tid = threadIdx.x;

    for (int idx = tid; idx < 384; idx += 256) {
        int s = idx >> 7, c = idx & 127;
        q_l[s][c + (c >> 5)] = q[b * 384 + idx];
    }

    const int n = tid >> 2, q4 = tid & 3;
    const float4* kg4 = (const float4*)(kbuf + ((size_t)b * 1024 + n0 + n) * 128 + q4 * 32);
    const int tg = tid >> 5, d0 = (tid & 31) * 4;
    const float* vp = vbuf + ((size_t)b * 1024 + n0 + tg * 8) * 128 + d0;

    float4 ka[8], kb2[8], va[8], vb2[8];
#pragma unroll
    for (int i = 0; i < 8; i++) ka[i] = kg4[i];     // sub-chunk 0 k
    __syncthreads();                                 // q_l ready

    const float* q0 = &q_l[0][q4 * 33];
    const float* q1 = &q_l[1][q4 * 33];
    const float* q2 = &q_l[2][q4 * 33];
#pragma unroll
    for (int sc = 0; sc < 4; sc++) {
        if (sc < 3) {
            const float4* kn = kg4 + (size_t)(sc + 1) * 2048;
#pragma unroll
            for (int i = 0; i < 8; i++) ((sc & 1) ? ka : kb2)[i] = kn[i];
        } else {
#pragma unroll
            for (int j = 0; j < 8; j++) va[j] = *(const float4*)(vp + (size_t)j * 128);
        }
        const float4* kc = (sc & 1) ? kb2 : ka;
        float p0 = 0.f, p1 = 0.f, p2 = 0.f;
#pragma unroll
        for (int i = 0; i < 8; i++) {
            float kx[4] = {kc[i].x, kc[i].y, kc[i].z, kc[i].w};
#pragma unroll
            for (int j = 0; j < 4; j++) {
                float vv = kx[j];
                p0 += q0[4 * i + j] * vv;
                p1 += q1[4 * i + j] * vv;
                p2 += q2[4 * i + j] * vv;
            }
        }
        p0 += __shfl_xor(p0, 1, 64); p0 += __shfl_xor(p0, 2, 64);
        p1 += __shfl_xor(p1, 1, 64); p1 += __shfl_xor(p1, 2, 64);
        p2 += __shfl_xor(p2, 1, 64); p2 += __shfl_xor(p2, 2, 64);
        if (q4 == 0) {
            lg[0][sc * 64 + n] = p0 * SCALE;
            lg[1][sc * 64 + n] = p1 * SCALE;
            lg[2][sc * 64 + n] = p2 * SCALE;
        }
    }
    __syncthreads();

    {
        float l0 = lg[0][tid], l1 = lg[1][tid], l2 = lg[2][tid];
        float m = fmaxf(l0, fmaxf(l1, l2));
        float e0 = expf(l0 - m), e1 = expf(l1 - m), e2 = expf(l2 - m);
        float inv = 1.f / (e0 + e1 + e2);
        w_l[0][tid] = e0 * inv; w_l[1][tid] = e1 * inv; w_l[2][tid] = e2 * inv;
        if (write_attn) {
            int nn = n0 + tid;
            attn_out[b * 3072 + nn]        = e0 * inv;
            attn_out[b * 3072 + 1024 + nn] = e1 * inv;
            attn_out[b * 3072 + 2048 + nn] = e2 * inv;
        }
    }
    __syncthreads();

    float4 a0 = {0.f, 0.f, 0.f, 0.f}, a1 = a0, a2 = a0;
#pragma unroll
    for (int sc = 0; sc < 4; sc++) {
        if (sc < 3) {
            const float* vn = vp + (size_t)(sc + 1) * 8192;
#pragma unroll
            for (int j = 0; j < 8; j++)
                ((sc & 1) ? va : vb2)[j] = *(const float4*)(vn + (size_t)j * 128);
        }
        const float4* vc = (sc & 1) ? vb2 : va;
#pragma unroll
        for (int j = 0; j < 8; j++) {
            float w0 = w_l[0][sc * 64 + tg * 8 + j];
            float w1 = w_l[1][sc * 64 + tg * 8 + j];
            float w2 = w_l[2][sc * 64 + tg * 8 + j];
            float4 vv = vc[j];
            a0.x += w0 * vv.x; a0.y += w0 * vv.y; a0.z += w0 * vv.z; a0.w += w0 * vv.w;
            a1.x += w1 * vv.x; a1.y += w1 * vv.y; a1.z += w1 * vv.z; a1.w += w1 * vv.w;
            a2.x += w2 * vv.x; a2.y += w2 * vv.y; a2.z += w2 * vv.z; a2.w += w2 * vv.w;
        }
    }
    *(float4*)&part[tg][0][d0] = a0;
    *(float4*)&part[tg][1][d0] = a1;
    *(float4*)&part[tg][2][d0] = a2;
    __syncthreads();

    for (int idx = tid; idx < 384; idx += 256) {
        int s = idx >> 7, d = idx & 127;
        float u = 0.f;
#pragma unroll
        for (int g = 0; g < 8; g++) u += part[g][s][d];
        upd_part[(((size_t)b * 4 + chunk) * 3 + s) * 128 + d] = u;
    }
}

// ====== fused GRU cell + LN + MLP residual + (LN_s + q for next iter) ========
// 768 threads, K-split on every dot phase: halves/quarters the serial
// load-chain depth and doubles waves/block (6 -> 12) vs the 384-thread
// version. Partials combined via LDS (reassociation only; W2/Wq were
// already K-split since R3 with identical absmax).
__global__ __launch_bounds__(768) void gru_mlp_kernel(
    const float* __restrict__ slots_in, const float* __restrict__ upd_part,
    const float4* __restrict__ WihT4, const float* __restrict__ bih,
    const float4* __restrict__ WhhT4, const float* __restrict__ bhh,
    const float* __restrict__ g_m, const float* __restrict__ b_m,
    const float4* __restrict__ W1T4, const float* __restrict__ b1,
    const float4* __restrict__ W2T4, const float* __restrict__ b2,
    const float* __restrict__ g_s, const float* __restrict__ b_s,
    const float4* __restrict__ WqT4, const float* __restrict__ bq,
    float* __restrict__ slots_out, float* __restrict__ q_out, int write_q)
{
    __shared__ float u4[4][128];
    __shared__ float u_l[128], h_l[128];
    __shared__ float gip[2][384], ghp[2][384];
    __shared__ float r_l[128], z_l[128], in_l[128], hn_l[128];
    __shared__ float n_l[128], hid_l[256];
    __shared__ float pp[512];                 // K-split partials (W1/W2/Wq)
    __shared__ float red[4];
    const int row = blockIdx.x, tid = threadIdx.x;
    const int bb_ = row / 3, ss = row - bb_ * 3;

    // ---- u-sum (4 chunk partials) + hprev load, fully parallel ----
    if (tid < 512) {
        int c = tid >> 7, d = tid & 127;
        u4[c][d] = upd_part[(((size_t)bb_ * 4 + c) * 3 + ss) * 128 + d];
    } else if (tid < 640) {
        int d = tid - 512;
        h_l[d] = slots_in[row * 128 + d];
    }
    __syncthreads();
    if (tid < 128)
        u_l[tid] = ((u4[0][tid] + u4[1][tid]) + u4[2][tid]) + u4[3][tid];
    __syncthreads();

    // ---- gates: 384 outputs x 2 K-halves (16 float4 iters each) ----
    {
        int half = (tid >= 384) ? 1 : 0;
        int out  = tid - half * 384;
        float gi = half ? 0.f : bih[out];
        float gh = half ? 0.f : bhh[out];
        int k0 = half * 16;
#pragma unroll 8
        for (int kq = k0; kq < k0 + 16; kq++) {
            float4 a = WihT4[kq * 384 + out];
            float4 c = WhhT4[kq * 384 + out];
            gi += u_l[4 * kq] * a.x + u_l[4 * kq + 1] * a.y
                + u_l[4 * kq + 2] * a.z + u_l[4 * kq + 3] * a.w;
            gh += h_l[4 * kq] * c.x + h_l[4 * kq + 1] * c.y
                + h_l[4 * kq + 2] * c.z + h_l[4 * kq + 3] * c.w;
        }
        gip[half][out] = gi;
        ghp[half][out] = gh;
    }
    __syncthreads();
    if (tid < 384) {
        float gi = gip[0][tid] + gip[1][tid];
        float gh = ghp[0][tid] + ghp[1][tid];
        if (tid < 128)      r_l[tid] = 1.f / (1.f + expf(-(gi + gh)));
        else if (tid < 256) z_l[tid - 128] = 1.f / (1.f + expf(-(gi + gh)));
        else { in_l[tid - 256] = gi; hn_l[tid - 256] = gh; }
    }
    __syncthreads();

    // ---- hnew + LN_m ----
    float hnew = 0.f;
    if (tid < 128) {
        float nn = tanhf(in_l[tid] + r_l[tid] * hn_l[tid]);
        hnew = (1.f - z_l[tid]) * nn + z_l[tid] * h_l[tid];
        float s = hnew, s2 = hnew * hnew;
#pragma unroll
        for (int off = 32; off >= 1; off >>= 1) {
            s += __shfl_down(s, off, 64); s2 += __shfl_down(s2, off, 64);
        }
        if ((tid & 63) == 0) { red[tid >> 6] = s; red[2 + (tid >> 6)] = s2; }
    }
    __syncthreads();
    if (tid < 128) {
        float S = red[0] + red[1], S2 = red[2] + red[3];
        float m1 = S * (1.f / 128.f);
        float r1 = rsqrtf(S2 * (1.f / 128.f) - m1 * m1 + EPS);
        n_l[tid] = (hnew - m1) * r1 * g_m[tid] + b_m[tid];
    }
    __syncthreads();

    // ---- W1 + gelu: 256 outputs x 2 K-halves ----
    if (tid < 512) {
        int half = tid >> 8, out = tid & 255;
        float a = half ? 0.f : b1[out];
        int k0 = half * 16;
#pragma unroll 8
        for (int kq = k0; kq < k0 + 16; kq++) {
            float4 w = W1T4[kq * 256 + out];
            a += n_l[4 * kq] * w.x + n_l[4 * kq + 1] * w.y
               + n_l[4 * kq + 2] * w.z + n_l[4 * kq + 3] * w.w;
        }
        pp[half * 256 + out] = a;
    }
    __syncthreads();
    if (tid < 256) {
        float a = pp[tid] + pp[256 + tid];
        a = 0.5f * a * (1.f + erff(a * 0.70710678118654752f));
        hid_l[tid] = a;
    }
    __syncthreads();

    // ---- W2: 128 outputs x 4 K-quarters (K=256 -> 16 iters each) ----
    if (tid < 512) {
        int qr = tid >> 7, out = tid & 127;
        float p = 0.f;
        int k0 = qr * 16;
#pragma unroll 8
        for (int kq = k0; kq < k0 + 16; kq++) {
            float4 w = W2T4[kq * 128 + out];
            p += hid_l[4 * kq] * w.x + hid_l[4 * kq + 1] * w.y
               + hid_l[4 * kq + 2] * w.z + hid_l[4 * kq + 3] * w.w;
        }
        pp[qr * 128 + out] = p;
    }
    __syncthreads();

    float snew = 0.f;
    if (tid < 128) {
        snew = hnew + b2[tid]
             + ((pp[tid] + pp[128 + tid]) + (pp[256 + tid] + pp[384 + tid]));
        slots_out[row * 128 + tid] = snew;
    }

    if (write_q) {
        // ---- LN_s ----
        if (tid < 128) {
            float t1 = snew, t2 = snew * snew;
#pragma unroll
            for (int off = 32; off >= 1; off >>= 1) {
                t1 += __shfl_down(t1, off, 64); t2 += __shfl_down(t2, off, 64);
            }
            if ((tid & 63) == 0) { red[tid >> 6] = t1; red[2 + (tid >> 6)] = t2; }
        }
        __syncthreads();
        if (tid < 128) {
            float T = red[0] + red[1], T2 = red[2] + red[3];
            float m2 = T * (1.f / 128.f);
            float r2 = rsqrtf(T2 * (1.f / 128.f) - m2 * m2 + EPS);
            n_l[tid] = (snew - m2) * r2 * g_s[tid] + b_s[tid];
        }
        __syncthreads();
        // ---- Wq: 128 outputs x 4 K-quarters (K=128 -> 8 iters each) ----
        if (tid < 512) {
            int qr = tid >> 7, out = tid & 127;
            float p = (qr == 0) ? bq[out] : 0.f;
            int k0 = qr * 8;
#pragma unroll 8
            for (int kq = k0; kq < k0 + 8; kq++) {
                float4 w = WqT4[kq * 128 + out];
                p += n_l[4 * kq] * w.x + n_l[4 * kq + 1] * w.y
                   + n_l[4 * kq + 2] * w.z + n_l[4 * kq + 3] * w.w;
            }
            pp[qr * 128 + out] = p;
        }
        __syncthreads();
        if (tid < 128)
            q_out[row * 128 + tid] =
                (pp[tid] + pp[128 + tid]) + (pp[256 + tid] + pp[384 + tid]);
    }
}

// ============================================================================
extern "C" void kernel_launch(void* const* d_in, const int* in_sizes, int n_in,
                              void* d_out, int out_size, void* d_ws, size_t ws_size,
                              hipStream_t stream)
{
    const float* patch   = (const float*)d_in[0];
    const float* noise   = (const float*)d_in[1];
    const float* slot_mu = (const float*)d_in[2];
    const float* slot_ls = (const float*)d_in[3];
    const float* Wp = (const float*)d_in[4];  const float* bp = (const float*)d_in[5];
    const float* g_in = (const float*)d_in[6]; const float* b_in = (const float*)d_in[7];
    const float* Wq = (const float*)d_in[8];  const float* bq = (const float*)d_in[9];
    const float* Wk = (const float*)d_in[10]; const float* bk = (const float*)d_in[11];
    const float* Wv = (const float*)d_in[12]; const float* bv = (const float*)d_in[13];
    const float* Wih = (const float*)d_in[14]; const float* bih = (const float*)d_in[15];
    const float* Whh = (const float*)d_in[16]; const float* bhh = (const float*)d_in[17];
    const float* g_s = (const float*)d_in[18]; const float* b_s = (const float*)d_in[19];
    const float* W1 = (const float*)d_in[20]; const float* b1 = (const float*)d_in[21];
    const float* W2 = (const float*)d_in[22]; const float* b2 = (const float*)d_in[23];
    const float* g_m = (const float*)d_in[24]; const float* b_m = (const float*)d_in[25];

    // ---- workspace layout ----
    float* kbuf = (float*)d_ws;                                   // 16777216 f32
    float* vbuf = kbuf + 16777216;                                // 16777216 f32
    unsigned short* w_hi = (unsigned short*)(vbuf + 16777216);    // 57344
    unsigned short* w_lo = w_hi + 57344;                          // 57344
    unsigned short* wp_hi = w_hi,        * wp_lo = w_lo;
    unsigned short* wk_hi = w_hi + 24576,* wk_lo = w_lo + 24576;
    unsigned short* wv_hi = w_hi + 40960,* wv_lo = w_lo + 40960;
    float4* wt4 = (float4*)(w_lo + 57344);                        // 45056 float4
    float4* wihT4 = wt4;
    float4* whhT4 = wt4 + 12288;
    float4* w1T4  = wt4 + 24576;
    float4* w2T4  = wt4 + 32768;
    float4* wqT4  = wt4 + 40960;
    float* slots = (float*)(wt4 + 45056);                         // 49152 f32
    float* qbuf  = slots + 49152;                                 // 49152 f32
    float* part  = qbuf + 49152;                                  // 196608 f32

    float* out_slots = (float*)d_out;                             // (B,K,H)
    float* out_attn  = (float*)d_out + 49152;                     // (B,K,N)

    prep_weights_kernel<<<400, 256, 0, stream>>>(
        Wp, Wk, Wv, Wih, Whh, W1, W2, Wq, w_hi, w_lo, wt4);

    // X = LN(patch @ Wp^T + bp) kept in LDS; k,v written directly.
    fused_proj_kv_kernel<<<2048, 256, 0, stream>>>(
        patch, wp_hi, wp_lo, wk_hi, wk_lo, wv_hi, wv_lo,
        bp, g_in, b_in, bk, bv, kbuf, vbuf);

    // slots init + LN + q0
    init_lnq_kernel<<<384, 128, 0, stream>>>(noise, slot_mu, slot_ls,
                                             g_s, b_s, wqT4, bq, slots, qbuf);

    for (int it = 0; it < 3; it++) {
        attn_kernel<<<dim3(4, 128), 256, 0, stream>>>(
            qbuf, kbuf, vbuf, part, out_attn, it == 2 ? 1 : 0);
        gru_mlp_kernel<<<384, 768, 0, stream>>>(
            slots, part, wihT4, bih, whhT4, bhh, g_m, b_m, w1T4, b1, w2T4, b2,
            g_s, b_s, wqT4, bq,
            (it == 2) ? out_slots : slots, qbuf, it == 2 ? 0 : 1);
    }
}

// Round 9
// 351.744 us; speedup vs baseline: 1.0406x; 1.0406x over previous
//
#include <hip/hip_runtime.h>
#include <math.h>

constexpr float EPS = 1e-5f;
constexpr float SCALE = 0.08838834764831845f; // 1/sqrt(128)

using f32x4  = __attribute__((ext_vector_type(4))) float;
using bf16x8 = __attribute__((ext_vector_type(8))) short;
using us8    = __attribute__((ext_vector_type(8))) unsigned short;

__device__ __forceinline__ unsigned short f2b_rne(float f) {
    unsigned int x = __float_as_uint(f);
    return (unsigned short)((x + 0x7fffu + ((x >> 16) & 1u)) >> 16);
}
// packed X word: hi bf16 in [31:16], lo bf16 in [15:0]; value = hi + lo
__device__ __forceinline__ float xrec(unsigned int w) {
    return __uint_as_float(w & 0xffff0000u) + __uint_as_float(w << 16);
}

// XOR-swizzled element offset into a [rows][32]-us tile; k8 = 8-elem col chunk.
__device__ __forceinline__ int swz32(int row, int k8) {
    int f = (row & 3) ^ ((row >> 2) & 3);
    return row * 32 + ((k8 ^ f) << 3);
}

// ====== one-time weight prep ======
// hi/lo: Wp only (fused phase 1). wt4 layout (float4):
//   WihT4[0,12288) WhhT4[12288,24576) W1T4[24576,32768) W2T4[32768,40960)
//   WqT4[40960,45056) WvT4[45056,49152)      -- x @ W^T packs
//   WkQ4[49152,53248)                        -- x @ W pack (TRANSPOSED: Wk[k][out])
__global__ __launch_bounds__(256) void prep_weights_kernel(
    const float* __restrict__ Wp, const float* __restrict__ Wk,
    const float* __restrict__ Wv, const float* __restrict__ Wih,
    const float* __restrict__ Whh, const float* __restrict__ W1,
    const float* __restrict__ W2, const float* __restrict__ Wq,
    unsigned short* __restrict__ hi, unsigned short* __restrict__ lo,
    float4* __restrict__ wt4)
{
    int idx = blockIdx.x * 256 + threadIdx.x; // 77824 total
    if (idx < 24576) {
        float v = Wp[idx];
        unsigned int bits = __float_as_uint(v);
        hi[idx] = (unsigned short)(bits >> 16);
        lo[idx] = f2b_rne(v - __uint_as_float(bits & 0xffff0000u));
    } else {
        int li = idx - 24576;
        float4 v;
        if (li < 49152) {
            const float* src; int OUT, base, K;
            if (li < 12288)      { src = Wih; OUT = 384; base = 0;     K = 128; }
            else if (li < 24576) { src = Whh; OUT = 384; base = 12288; K = 128; }
            else if (li < 32768) { src = W1;  OUT = 256; base = 24576; K = 128; }
            else if (li < 40960) { src = W2;  OUT = 128; base = 32768; K = 256; }
            else if (li < 45056) { src = Wq;  OUT = 128; base = 40960; K = 128; }
            else                 { src = Wv;  OUT = 128; base = 45056; K = 128; }
            int l2 = li - base;
            int kq = l2 / OUT, t = l2 - kq * OUT;
            v.x = src[(size_t)t * K + 4 * kq];
            v.y = src[(size_t)t * K + 4 * kq + 1];
            v.z = src[(size_t)t * K + 4 * kq + 2];
            v.w = src[(size_t)t * K + 4 * kq + 3];
        } else { // WkQ4: transposed pack for qk = q @ Wk
            int l2 = li - 49152;
            int kq = l2 >> 7, t = l2 & 127;
            v.x = Wk[(size_t)(4 * kq + 0) * 128 + t];
            v.y = Wk[(size_t)(4 * kq + 1) * 128 + t];
            v.z = Wk[(size_t)(4 * kq + 2) * 128 + t];
            v.w = Wk[(size_t)(4 * kq + 3) * 128 + t];
        }
        wt4[li] = v;
    }
}

// ========== fused: X = LN(patch @ Wp^T + bp) -> packed u32 hi|lo ============
// R6 phase 1 (verified) + LN epilogue straight to global; phase 2 GONE
// (k,v eliminated algebraically). LDS 24 KB -> 4 blocks/CU.
__global__ __launch_bounds__(256, 4) void fused_proj_x_kernel(
    const float* __restrict__ patch,
    const unsigned short* __restrict__ Wphi, const unsigned short* __restrict__ Wplo,
    const float* __restrict__ biasp, const float* __restrict__ g_in,
    const float* __restrict__ b_in, unsigned int* __restrict__ xbuf)
{
    __shared__ __align__(16) unsigned short mem[12288];

    const int tid  = threadIdx.x;
    const int lane = tid & 63, wave = tid >> 6;
    const int ln15 = lane & 15, quad = lane >> 4;
    const int bid  = blockIdx.x;
    const int m0   = ((bid & 7) * 256 + (bid >> 3)) * 64; // XCD swizzle (2048%8==0)

    const int wrow = wave * 16;
    f32x4 acc1[8];
#pragma unroll
    for (int nt = 0; nt < 8; nt++)
#pragma unroll
        for (int r = 0; r < 4; r++) acc1[nt][r] = 0.f;

    const int arow = tid >> 2, ak8 = tid & 3;
    const float* aptr = patch + (size_t)(m0 + arow) * 192 + ak8 * 8;
    float4 pa[6][2];
#pragma unroll
    for (int t6 = 0; t6 < 6; t6++) {
        pa[t6][0] = *(const float4*)(aptr + t6 * 32);
        pa[t6][1] = *(const float4*)(aptr + t6 * 32 + 4);
    }
    us8 pbh[2], pbl[2];
    int boff[2];
#pragma unroll
    for (int i = 0; i < 2; i++) {
        int c = tid + 256 * i;
        boff[i] = (c >> 2) * 192 + (c & 3) * 8;
        pbh[i] = *(const us8*)(Wphi + boff[i]);
        pbl[i] = *(const us8*)(Wplo + boff[i]);
    }

    const int ea = swz32(wrow + ln15, quad);

#pragma unroll
    for (int st = 0; st < 6; st++) {
        {
            float va[8] = {pa[st][0].x, pa[st][0].y, pa[st][0].z, pa[st][0].w,
                           pa[st][1].x, pa[st][1].y, pa[st][1].z, pa[st][1].w};
            us8 h, l;
#pragma unroll
            for (int j = 0; j < 8; j++) {
                unsigned int bits = __float_as_uint(va[j]);
                h[j] = (unsigned short)(bits >> 16);
                l[j] = f2b_rne(va[j] - __uint_as_float(bits & 0xffff0000u));
            }
            int e = swz32(arow, ak8);
            *(us8*)&mem[e]        = h;
            *(us8*)&mem[2048 + e] = l;
        }
#pragma unroll
        for (int i = 0; i < 2; i++) {
            int c = tid + 256 * i;
            int e = swz32(c >> 2, c & 3);
            *(us8*)&mem[4096 + e] = pbh[i];
            *(us8*)&mem[8192 + e] = pbl[i];
        }
        __syncthreads();

        if (st < 5) {
            int kn = (st + 1) * 32;
#pragma unroll
            for (int i = 0; i < 2; i++) {
                pbh[i] = *(const us8*)(Wphi + boff[i] + kn);
                pbl[i] = *(const us8*)(Wplo + boff[i] + kn);
            }
        }

        bf16x8 ah = *(const bf16x8*)&mem[ea];
        bf16x8 al = *(const bf16x8*)&mem[2048 + ea];
#pragma unroll
        for (int nt = 0; nt < 8; nt++) {
            int eb = swz32(nt * 16 + ln15, quad);
            bf16x8 bh = *(const bf16x8*)&mem[4096 + eb];
            bf16x8 bl = *(const bf16x8*)&mem[8192 + eb];
            acc1[nt] = __builtin_amdgcn_mfma_f32_16x16x32_bf16(ah, bh, acc1[nt], 0, 0, 0);
            acc1[nt] = __builtin_amdgcn_mfma_f32_16x16x32_bf16(ah, bl, acc1[nt], 0, 0, 0);
            acc1[nt] = __builtin_amdgcn_mfma_f32_16x16x32_bf16(al, bh, acc1[nt], 0, 0, 0);
        }
        __syncthreads();
    }

    // ---- LN epilogue -> packed X to global ----
    float bb[8], gg[8], be[8];
#pragma unroll
    for (int nt = 0; nt < 8; nt++) {
        int col = nt * 16 + ln15;
        bb[nt] = biasp[col]; gg[nt] = g_in[col]; be[nt] = b_in[col];
    }
#pragma unroll
    for (int nt = 0; nt < 8; nt++)
#pragma unroll
        for (int r = 0; r < 4; r++) acc1[nt][r] += bb[nt];

    float mu[4], rs[4];
#pragma unroll
    for (int r = 0; r < 4; r++) {
        float s = 0.f, s2 = 0.f;
#pragma unroll
        for (int nt = 0; nt < 8; nt++) {
            float v = acc1[nt][r];
            s += v; s2 += v * v;
        }
#pragma unroll
        for (int off = 1; off < 16; off <<= 1) {
            s  += __shfl_xor(s,  off, 64);
            s2 += __shfl_xor(s2, off, 64);
        }
        float m = s * (1.f / 128.f);
        mu[r] = m;
        rs[r] = rsqrtf(s2 * (1.f / 128.f) - m * m + EPS);
    }
#pragma unroll
    for (int nt = 0; nt < 8; nt++)
#pragma unroll
        for (int r = 0; r < 4; r++) {
            float v = (acc1[nt][r] - mu[r]) * rs[r] * gg[nt] + be[nt];
            unsigned int bits = __float_as_uint(v);
            unsigned int hi = bits & 0xffff0000u;
            unsigned int word = hi | (unsigned int)f2b_rne(v - __uint_as_float(hi));
            size_t o = (size_t)(m0 + wrow + quad * 4 + r) * 128 + nt * 16 + ln15;
            xbuf[o] = word;
        }
}

// =================== init slots + LN + q -> qk, qb ===========================
__global__ __launch_bounds__(128) void init_lnq_kernel(
    const float* __restrict__ noise, const float* __restrict__ smu,
    const float* __restrict__ sls, const float* __restrict__ g_s,
    const float* __restrict__ b_s, const float4* __restrict__ WqT4,
    const float* __restrict__ bq, const float4* __restrict__ WkQ4,
    const float* __restrict__ bk, float* __restrict__ slots,
    float* __restrict__ qk_out, float* __restrict__ qb_out)
{
    __shared__ float s_l[128];
    __shared__ float red[4];
    const int row = blockIdx.x, tid = threadIdx.x;
    const int k = row % 3;
    float x = smu[k * 128 + tid] + expf(sls[k * 128 + tid]) * noise[row * 128 + tid];
    slots[row * 128 + tid] = x;

    float s = x, s2 = x * x;
#pragma unroll
    for (int off = 32; off >= 1; off >>= 1) {
        s += __shfl_down(s, off, 64); s2 += __shfl_down(s2, off, 64);
    }
    if ((tid & 63) == 0) { red[tid >> 6] = s; red[2 + (tid >> 6)] = s2; }
    __syncthreads();
    float S = red[0] + red[1], S2 = red[2] + red[3];
    float m = S * (1.f / 128.f);
    float r = rsqrtf(S2 * (1.f / 128.f) - m * m + EPS);
    s_l[tid] = (x - m) * r * g_s[tid] + b_s[tid];
    __syncthreads();

    float a = bq[tid];
#pragma unroll 8
    for (int kq = 0; kq < 32; kq++) {
        float4 w = WqT4[kq * 128 + tid];
        a += s_l[4 * kq] * w.x + s_l[4 * kq + 1] * w.y
           + s_l[4 * kq + 2] * w.z + s_l[4 * kq + 3] * w.w;
    }
    __syncthreads();            // all s_l reads done before reuse
    s_l[tid] = a;               // s_l now holds q
    float pb = a * bk[tid];
#pragma unroll
    for (int off = 32; off >= 1; off >>= 1) pb += __shfl_down(pb, off, 64);
    if ((tid & 63) == 0) red[tid >> 6] = pb;
    __syncthreads();

    float qkv = 0.f;
#pragma unroll 8
    for (int kq = 0; kq < 32; kq++) {
        float4 w = WkQ4[kq * 128 + tid];
        qkv += s_l[4 * kq] * w.x + s_l[4 * kq + 1] * w.y
             + s_l[4 * kq + 2] * w.z + s_l[4 * kq + 3] * w.w;
    }
    qk_out[row * 128 + tid] = qkv;
    if (tid == 0) qb_out[row] = red[0] + red[1];
}

// ============ attention over X stream: logits -> softmax -> uX ===============
// logits[s,n] = qk[s]·X[n] + qb[s]; w = softmax over slots (per token);
// uX[s] += w[s,n]·X[n]; wsum[s] += w[s,n]. One X stream (packed u32),
// 256-token chunks, grid (4,B), R7 phase-separated dbuf structure.
__global__ __launch_bounds__(256) void attn_kernel(
    const float* __restrict__ qk, const float* __restrict__ qb,
    const unsigned int* __restrict__ xbuf, float* __restrict__ uX_part,
    float* __restrict__ wsum_part, float* __restrict__ attn_out, int write_attn)
{
    __shared__ float qk_l[3][132];
    __shared__ float lg[3][256];
    __shared__ float w_l[3][256];
    __shared__ float part[8][3][128];
    __shared__ float wred[3][4];
    const int b = blockIdx.y, chunk = blockIdx.x, n0 = chunk * 256, tid = threadIdx.x;

    for (int idx = tid; idx < 384; idx += 256) {
        int s = idx >> 7, c = idx & 127;
        qk_l[s][c + (c >> 5)] = qk[b * 384 + idx];
    }
    const float qb0 = qb[b * 3], qb1 = qb[b * 3 + 1], qb2 = qb[b * 3 + 2];

    const int n = tid >> 2, q4 = tid & 3;
    const uint4* xg = (const uint4*)(xbuf + ((size_t)b * 1024 + n0 + n) * 128 + q4 * 32);
    const int tg = tid >> 5, d0 = (tid & 31) * 4;
    const unsigned int* xp = xbuf + ((size_t)b * 1024 + n0 + tg * 8) * 128 + d0;

    uint4 ka[8], kb2_[8], va[8], vb2_[8];
#pragma unroll
    for (int i = 0; i < 8; i++) ka[i] = xg[i];      // sub-chunk 0
    __syncthreads();                                 // qk_l ready

    // ---- phase 1: logits, 4 sub-chunks, dbuf ----
    const float* q0 = &qk_l[0][q4 * 33];
    const float* q1 = &qk_l[1][q4 * 33];
    const float* q2 = &qk_l[2][q4 * 33];
#pragma unroll
    for (int sc = 0; sc < 4; sc++) {
        if (sc < 3) {
            const uint4* kn = xg + (size_t)(sc + 1) * 2048;
#pragma unroll
            for (int i = 0; i < 8; i++) ((sc & 1) ? ka : kb2_)[i] = kn[i];
        } else { // last sub-chunk: issue PV prologue loads instead
#pragma unroll
            for (int j = 0; j < 8; j++) va[j] = *(const uint4*)(xp + (size_t)j * 128);
        }
        const uint4* kc = (sc & 1) ? kb2_ : ka;
        float p0 = 0.f, p1 = 0.f, p2 = 0.f;
#pragma unroll
        for (int i = 0; i < 8; i++) {
            unsigned int kw[4] = {kc[i].x, kc[i].y, kc[i].z, kc[i].w};
#pragma unroll
            for (int j = 0; j < 4; j++) {
                float xv = xrec(kw[j]);
                p0 += q0[4 * i + j] * xv;
                p1 += q1[4 * i + j] * xv;
                p2 += q2[4 * i + j] * xv;
            }
        }
        p0 += __shfl_xor(p0, 1, 64); p0 += __shfl_xor(p0, 2, 64);
        p1 += __shfl_xor(p1, 1, 64); p1 += __shfl_xor(p1, 2, 64);
        p2 += __shfl_xor(p2, 1, 64); p2 += __shfl_xor(p2, 2, 64);
        if (q4 == 0) {
            lg[0][sc * 64 + n] = (p0 + qb0) * SCALE;
            lg[1][sc * 64 + n] = (p1 + qb1) * SCALE;
            lg[2][sc * 64 + n] = (p2 + qb2) * SCALE;
        }
    }
    __syncthreads();

    // ---- phase 2: softmax over slots (token = tid) + wsum reduce ----
    {
        float l0 = lg[0][tid], l1 = lg[1][tid], l2 = lg[2][tid];
        float m = fmaxf(l0, fmaxf(l1, l2));
        float e0 = expf(l0 - m), e1 = expf(l1 - m), e2 = expf(l2 - m);
        float inv = 1.f / (e0 + e1 + e2);
        float w0 = e0 * inv, w1 = e1 * inv, w2 = e2 * inv;
        w_l[0][tid] = w0; w_l[1][tid] = w1; w_l[2][tid] = w2;
        if (write_attn) {
            int nn = n0 + tid;
            attn_out[b * 3072 + nn]        = w0;
            attn_out[b * 3072 + 1024 + nn] = w1;
            attn_out[b * 3072 + 2048 + nn] = w2;
        }
        float s0 = w0, s1 = w1, s2 = w2;
#pragma unroll
        for (int off = 1; off < 64; off <<= 1) {
            s0 += __shfl_xor(s0, off, 64);
            s1 += __shfl_xor(s1, off, 64);
            s2 += __shfl_xor(s2, off, 64);
        }
        if ((tid & 63) == 0) {
            int wv = tid >> 6;
            wred[0][wv] = s0; wred[1][wv] = s1; wred[2][wv] = s2;
        }
    }
    __syncthreads();

    // ---- phase 3: uX accumulate, 4 sub-chunks, dbuf ----
    float4 a0 = {0.f, 0.f, 0.f, 0.f}, a1 = a0, a2 = a0;
#pragma unroll
    for (int sc = 0; sc < 4; sc++) {
        if (sc < 3) {
            const unsigned int* vn = xp + (size_t)(sc + 1) * 8192;
#pragma unroll
            for (int j = 0; j < 8; j++)
                ((sc & 1) ? va : vb2_)[j] = *(const uint4*)(vn + (size_t)j * 128);
        }
        const uint4* vc = (sc & 1) ? vb2_ : va;
#pragma unroll
        for (int j = 0; j < 8; j++) {
            float w0 = w_l[0][sc * 64 + tg * 8 + j];
            float w1 = w_l[1][sc * 64 + tg * 8 + j];
            float w2 = w_l[2][sc * 64 + tg * 8 + j];
            unsigned int vw[4] = {vc[j].x, vc[j].y, vc[j].z, vc[j].w};
            float x0 = xrec(vw[0]), x1 = xrec(vw[1]), x2 = xrec(vw[2]), x3 = xrec(vw[3]);
            a0.x += w0 * x0; a0.y += w0 * x1; a0.z += w0 * x2; a0.w += w0 * x3;
            a1.x += w1 * x0; a1.y += w1 * x1; a1.z += w1 * x2; a1.w += w1 * x3;
            a2.x += w2 * x0; a2.y += w2 * x1; a2.z += w2 * x2; a2.w += w2 * x3;
        }
    }
    *(float4*)&part[tg][0][d0] = a0;
    *(float4*)&part[tg][1][d0] = a1;
    *(float4*)&part[tg][2][d0] = a2;
    __syncthreads();

    for (int idx = tid; idx < 384; idx += 256) {
        int s = idx >> 7, d = idx & 127;
        float u = 0.f;
#pragma unroll
        for (int g = 0; g < 8; g++) u += part[g][s][d];
        uX_part[(((size_t)b * 4 + chunk) * 3 + s) * 128 + d] = u;
    }
    if (tid < 3)
        wsum_part[((size_t)b * 4 + chunk) * 3 + tid] =
            (wred[tid][0] + wred[tid][1]) + (wred[tid][2] + wred[tid][3]);
}

// ====== GRU + LN + MLP residual; u = uX@Wv^T + wsum·bv; out qk,qb ===========
__global__ __launch_bounds__(384) void gru_mlp_kernel(
    const float* __restrict__ slots_in, const float* __restrict__ uX_part,
    const float* __restrict__ wsum_part,
    const float4* __restrict__ WvT4, const float* __restrict__ bv,
    const float4* __restrict__ WihT4, const float* __restrict__ bih,
    const float4* __restrict__ WhhT4, const float* __restrict__ bhh,
    const float* __restrict__ g_m, const float* __restrict__ b_m,
    const float4* __restrict__ W1T4, const float* __restrict__ b1,
    const float4* __restrict__ W2T4, const float* __restrict__ b2,
    const float* __restrict__ g_s, const float* __restrict__ b_s,
    const float4* __restrict__ WqT4, const float* __restrict__ bq,
    const float4* __restrict__ WkQ4, const float* __restrict__ bk,
    float* __restrict__ slots_out, float* __restrict__ qk_out,
    float* __restrict__ qb_out, int write_q)
{
    __shared__ float u2[2][128];
    __shared__ float uxs[128], u_l[128], h_l[128];
    __shared__ float r_l[128], z_l[128], in_l[128], hn_l[128];
    __shared__ float n_l[128], hid_l[256], w2p[256];
    __shared__ float red[4];
    __shared__ float wsum_s;
    const int row = blockIdx.x, tid = threadIdx.x;
    const int bb_ = row / 3, ss = row - bb_ * 3;

    if (tid < 256) {
        int col = tid & 127, half = tid >> 7;
        const float* up = uX_part + (((size_t)bb_ * 4 + half * 2) * 3 + ss) * 128 + col;
        u2[half][col] = up[0] + up[384];
        if (half == 0) h_l[col] = slots_in[row * 128 + col];
    } else if (tid == 256) {
        const float* wp = wsum_part + (size_t)bb_ * 12 + ss;
        wsum_s = ((wp[0] + wp[3]) + wp[6]) + wp[9];
    }
    __syncthreads();
    if (tid < 128) uxs[tid] = u2[0][tid] + u2[1][tid];
    __syncthreads();

    // ---- u = uxs @ Wv^T + wsum·bv (K-halves) ----
    if (tid < 256) {
        int out = tid & 127, half = tid >> 7;
        float p = 0.f;
#pragma unroll 8
        for (int kq = half * 16; kq < half * 16 + 16; kq++) {
            float4 w = WvT4[kq * 128 + out];
            p += uxs[4 * kq] * w.x + uxs[4 * kq + 1] * w.y
               + uxs[4 * kq + 2] * w.z + uxs[4 * kq + 3] * w.w;
        }
        w2p[tid] = p;
    }
    __syncthreads();
    if (tid < 128) u_l[tid] = (w2p[tid] + w2p[128 + tid]) + wsum_s * bv[tid];
    __syncthreads();

    // ---- gates ----
    if (tid < 384) {
        float gi = bih[tid], gh = bhh[tid];
#pragma unroll 8
        for (int kq = 0; kq < 32; kq++) {
            float4 a = WihT4[kq * 384 + tid];
            float4 c = WhhT4[kq * 384 + tid];
            gi += u_l[4 * kq] * a.x + u_l[4 * kq + 1] * a.y
                + u_l[4 * kq + 2] * a.z + u_l[4 * kq + 3] * a.w;
            gh += h_l[4 * kq] * c.x + h_l[4 * kq + 1] * c.y
                + h_l[4 * kq + 2] * c.z + h_l[4 * kq + 3] * c.w;
        }
        if (tid < 128)      r_l[tid] = 1.f / (1.f + expf(-(gi + gh)));
        else if (tid < 256) z_l[tid - 128] = 1.f / (1.f + expf(-(gi + gh)));
        else { in_l[tid - 256] = gi; hn_l[tid - 256] = gh; }
    }
    __syncthreads();

    float hnew = 0.f;
    if (tid < 128) {
        float nn = tanhf(in_l[tid] + r_l[tid] * hn_l[tid]);
        hnew = (1.f - z_l[tid]) * nn + z_l[tid] * h_l[tid];
        float s = hnew, s2 = hnew * hnew;
#pragma unroll
        for (int off = 32; off >= 1; off >>= 1) {
            s += __shfl_down(s, off, 64); s2 += __shfl_down(s2, off, 64);
        }
        if ((tid & 63) == 0) { red[tid >> 6] = s; red[2 + (tid >> 6)] = s2; }
    }
    __syncthreads();
    if (tid < 128) {
        float S = red[0] + red[1], S2 = red[2] + red[3];
        float m1 = S * (1.f / 128.f);
        float r1 = rsqrtf(S2 * (1.f / 128.f) - m1 * m1 + EPS);
        n_l[tid] = (hnew - m1) * r1 * g_m[tid] + b_m[tid];
    }
    __syncthreads();

    if (tid < 256) { // W1 + gelu
        float a = b1[tid];
#pragma unroll 8
        for (int kq = 0; kq < 32; kq++) {
            float4 w = W1T4[kq * 256 + tid];
            a += n_l[4 * kq] * w.x + n_l[4 * kq + 1] * w.y
               + n_l[4 * kq + 2] * w.z + n_l[4 * kq + 3] * w.w;
        }
        a = 0.5f * a * (1.f + erff(a * 0.70710678118654752f));
        hid_l[tid] = a;
    }
    __syncthreads();

    if (tid < 256) { // W2, K=256 halves
        int out = tid & 127, half = tid >> 7;
        float p = 0.f;
#pragma unroll 8
        for (int kq = half * 32; kq < half * 32 + 32; kq++) {
            float4 w = W2T4[kq * 128 + out];
            p += hid_l[4 * kq] * w.x + hid_l[4 * kq + 1] * w.y
               + hid_l[4 * kq + 2] * w.z + hid_l[4 * kq + 3] * w.w;
        }
        w2p[tid] = p;
    }
    __syncthreads();

    float snew = 0.f;
    if (tid < 128) {
        snew = hnew + b2[tid] + (w2p[tid] + w2p[128 + tid]);
        slots_out[row * 128 + tid] = snew;
    }

    if (write_q) {
        if (tid < 128) {
            float t1 = snew, t2 = snew * snew;
#pragma unroll
            for (int off = 32; off >= 1; off >>= 1) {
                t1 += __shfl_down(t1, off, 64); t2 += __shfl_down(t2, off, 64);
            }
            if ((tid & 63) == 0) { red[tid >> 6] = t1; red[2 + (tid >> 6)] = t2; }
        }
        __syncthreads();
        if (tid < 128) {
            float T = red[0] + red[1], T2 = red[2] + red[3];
            float m2 = T * (1.f / 128.f);
            float r2 = rsqrtf(T2 * (1.f / 128.f) - m2 * m2 + EPS);
            n_l[tid] = (snew - m2) * r2 * g_s[tid] + b_s[tid];
        }
        __syncthreads();
        if (tid < 256) { // q = LN_s @ Wq^T + bq, K-halves
            int out = tid & 127, half = tid >> 7;
            float p = (half == 0) ? bq[out] : 0.f;
#pragma unroll 8
            for (int kq = half * 16; kq < half * 16 + 16; kq++) {
                float4 w = WqT4[kq * 128 + out];
                p += n_l[4 * kq] * w.x + n_l[4 * kq + 1] * w.y
                   + n_l[4 * kq + 2] * w.z + n_l[4 * kq + 3] * w.w;
            }
            w2p[tid] = p;
        }
        __syncthreads();
        if (tid < 128) { // q value -> n_l; qb partial reduce
            float qv = w2p[tid] + w2p[128 + tid];
            n_l[tid] = qv;
            float pb = qv * bk[tid];
#pragma unroll
            for (int off = 32; off >= 1; off >>= 1) pb += __shfl_down(pb, off, 64);
            if ((tid & 63) == 0) red[tid >> 6] = pb;
        }
        __syncthreads();
        if (tid == 0) qb_out[row] = red[0] + red[1];
        if (tid < 256) { // qk = q @ Wk (transposed pack), K-halves
            int out = tid & 127, half = tid >> 7;
            float p = 0.f;
#pragma unroll 8
            for (int kq = half * 16; kq < half * 16 + 16; kq++) {
                float4 w = WkQ4[kq * 128 + out];
                p += n_l[4 * kq] * w.x + n_l[4 * kq + 1] * w.y
                   + n_l[4 * kq + 2] * w.z + n_l[4 * kq + 3] * w.w;
            }
            hid_l[half * 128 + out] = p;
        }
        __syncthreads();
        if (tid < 128) qk_out[row * 128 + tid] = hid_l[tid] + hid_l[128 + tid];
    }
}

// ============================================================================
extern "C" void kernel_launch(void* const* d_in, const int* in_sizes, int n_in,
                              void* d_out, int out_size, void* d_ws, size_t ws_size,
                              hipStream_t stream)
{
    const float* patch   = (const float*)d_in[0];
    const float* noise   = (const float*)d_in[1];
    const float* slot_mu = (const float*)d_in[2];
    const float* slot_ls = (const float*)d_in[3];
    const float* Wp = (const float*)d_in[4];  const float* bp = (const float*)d_in[5];
    const float* g_in = (const float*)d_in[6]; const float* b_in = (const float*)d_in[7];
    const float* Wq = (const float*)d_in[8];  const float* bq = (const float*)d_in[9];
    const float* Wk = (const float*)d_in[10]; const float* bk = (const float*)d_in[11];
    const float* Wv = (const float*)d_in[12]; const float* bv = (const float*)d_in[13];
    const float* Wih = (const float*)d_in[14]; const float* bih = (const float*)d_in[15];
    const float* Whh = (const float*)d_in[16]; const float* bhh = (const float*)d_in[17];
    const float* g_s = (const float*)d_in[18]; const float* b_s = (const float*)d_in[19];
    const float* W1 = (const float*)d_in[20]; const float* b1 = (const float*)d_in[21];
    const float* W2 = (const float*)d_in[22]; const float* b2 = (const float*)d_in[23];
    const float* g_m = (const float*)d_in[24]; const float* b_m = (const float*)d_in[25];

    // ---- workspace layout (~66 MB) ----
    unsigned int* xbuf = (unsigned int*)d_ws;                     // 16777216 u32
    unsigned short* wp_hi = (unsigned short*)(xbuf + 16777216);   // 24576
    unsigned short* wp_lo = wp_hi + 24576;                        // 24576
    float4* wt4 = (float4*)(wp_lo + 24576);                       // 53248 float4
    float4* wihT4 = wt4;
    float4* whhT4 = wt4 + 12288;
    float4* w1T4  = wt4 + 24576;
    float4* w2T4  = wt4 + 32768;
    float4* wqT4  = wt4 + 40960;
    float4* wvT4  = wt4 + 45056;
    float4* wkQ4  = wt4 + 49152;
    float* slots  = (float*)(wt4 + 53248);                        // 49152 f32
    float* qkbuf  = slots + 49152;                                // 49152 f32
    float* qbbuf  = qkbuf + 49152;                                // 384 f32
    float* part   = qbbuf + 384;                                  // 196608 f32
    float* wsum   = part + 196608;                                // 1536 f32

    float* out_slots = (float*)d_out;                             // (B,K,H)
    float* out_attn  = (float*)d_out + 49152;                     // (B,K,N)

    prep_weights_kernel<<<304, 256, 0, stream>>>(
        Wp, Wk, Wv, Wih, Whh, W1, W2, Wq, wp_hi, wp_lo, wt4);

    // X = LN(patch @ Wp^T + bp) -> packed u32 (k,v never materialized)
    fused_proj_x_kernel<<<2048, 256, 0, stream>>>(
        patch, wp_hi, wp_lo, bp, g_in, b_in, xbuf);

    // slots init + LN + q0 -> qk0, qb0
    init_lnq_kernel<<<384, 128, 0, stream>>>(noise, slot_mu, slot_ls,
                                             g_s, b_s, wqT4, bq, wkQ4, bk,
                                             slots, qkbuf, qbbuf);

    for (int it = 0; it < 3; it++) {
        attn_kernel<<<dim3(4, 128), 256, 0, stream>>>(
            qkbuf, qbbuf, xbuf, part, wsum, out_attn, it == 2 ? 1 : 0);
        gru_mlp_kernel<<<384, 384, 0, stream>>>(
            slots, part, wsum, wvT4, bv, wihT4, bih, whhT4, bhh, g_m, b_m,
            w1T4, b1, w2T4, b2, g_s, b_s, wqT4, bq, wkQ4, bk,
            (it == 2) ? out_slots : slots, qkbuf, qbbuf, it == 2 ? 0 : 1);
    }
}